// Round 22
// baseline (313.331 us; speedup 1.0000x reference)
//
#include <hip/hip_runtime.h>
#include <math.h>

#define NN 8192
#define IN_DIM 128
#define THETA_DIM 256
#define OUT_DIM 64
#define LSTR 68   // LDS row stride in halfs (k_spmm only)

#define AS1 __attribute__((address_space(1)))
#define AS3 __attribute__((address_space(3)))

typedef _Float16 half_t;
typedef _Float16 f16x8 __attribute__((ext_vector_type(8)));
typedef _Float16 f16x4 __attribute__((ext_vector_type(4)));
typedef float f32x4 __attribute__((ext_vector_type(4)));

// ws layout (float offsets)
#define WS_SCALE 0
#define WS_SHIFT 128
#define WS_SUM   256
#define WS_SQ    384
#define WS_ROWSUM 512
#define WS_D     8704
#define WS_HN    16896
#define WS_HX    (WS_HN + NN*IN_DIM)
#define WS_Z     (WS_HX + NN*THETA_DIM)
#define WS_OBUF  (WS_Z + NN*OUT_DIM)
#define WS_ZDHT  (WS_OBUF + NN*OUT_DIM)       // f16 [64][8192]

// zero: [WS_SUM, WS_D) = 2112 float4 (9 blocks) + obuf 131072 float4 (512 blocks)
__global__ __launch_bounds__(256) void k_zero(float* __restrict__ ws) {
    int b = blockIdx.x, tid = threadIdx.x;
    float4 z = (float4){0.f, 0.f, 0.f, 0.f};
    if (b < 9) {
        int i = b * 256 + tid;
        if (i < 2112) ((float4*)(ws + WS_SUM))[i] = z;
    } else {
        int i = (b - 9) * 256 + tid;
        ((float4*)(ws + WS_OBUF))[i] = z;
    }
}

__global__ __launch_bounds__(256) void k_stats(const float* __restrict__ H, float* __restrict__ ws) {
    int tid = threadIdx.x;
    int c = tid & 127, h = tid >> 7;
    int rb = blockIdx.x * 32;
    float s = 0.f, q = 0.f;
    for (int r = h; r < 32; r += 2) {
        float v = H[(size_t)(rb + r) * IN_DIM + c];
        s += v; q += v * v;
    }
    atomicAdd(&ws[WS_SUM + c], s);
    atomicAdd(&ws[WS_SQ + c], q);
}

__global__ void k_finalize(const float* __restrict__ gamma, const float* __restrict__ beta, float* __restrict__ ws) {
    int c = threadIdx.x;
    float mean = ws[WS_SUM + c] * (1.f / NN);
    float var  = ws[WS_SQ + c] * (1.f / NN) - mean * mean;
    float rstd = 1.f / sqrtf(var + 1e-5f);
    float sc = rstd * gamma[c];
    ws[WS_SCALE + c] = sc;
    ws[WS_SHIFT + c] = beta[c] - mean * sc;
}

// fused: BN-normalize H tile inline, then Hx = (Hn @ W1 + b1) f16 AND Y = Hn @ Wout + bout
__global__ __launch_bounds__(256) void k_proj(const float* __restrict__ H, const float* __restrict__ ws,
                                              const float* __restrict__ W1, const float* __restrict__ b1,
                                              const float* __restrict__ Wout, const float* __restrict__ bout,
                                              half_t* __restrict__ Hx, float* __restrict__ Y) {
    __shared__ float HnS[32 * IN_DIM];
    int tid = threadIdx.x;
    int row0 = blockIdx.x * 32;
    const float4* src = (const float4*)(H + (size_t)row0 * IN_DIM);
    float4* dst = (float4*)HnS;
#pragma unroll
    for (int q = 0; q < 4; q++) {
        int f4i = q * 256 + tid;
        int cb = (f4i & 31) * 4;
        float4 v = src[f4i];
        float4 sc = *(const float4*)&ws[WS_SCALE + cb];
        float4 sh = *(const float4*)&ws[WS_SHIFT + cb];
        v.x = v.x * sc.x + sh.x; v.y = v.y * sc.y + sh.y;
        v.z = v.z * sc.z + sh.z; v.w = v.w * sc.w + sh.w;
        dst[f4i] = v;
    }
    __syncthreads();

    {
        int c = tid;
        float acc[32];
#pragma unroll
        for (int r = 0; r < 32; r++) acc[r] = 0.f;
        for (int k0 = 0; k0 < IN_DIM; k0 += 4) {
            float w0 = W1[(size_t)(k0 + 0) * THETA_DIM + c];
            float w1 = W1[(size_t)(k0 + 1) * THETA_DIM + c];
            float w2 = W1[(size_t)(k0 + 2) * THETA_DIM + c];
            float w3 = W1[(size_t)(k0 + 3) * THETA_DIM + c];
#pragma unroll
            for (int r = 0; r < 32; r++) {
                float4 h = *(const float4*)&HnS[r * IN_DIM + k0];
                acc[r] += h.x * w0 + h.y * w1 + h.z * w2 + h.w * w3;
            }
        }
        float bb = b1[c];
#pragma unroll
        for (int r = 0; r < 32; r++) Hx[(size_t)(row0 + r) * THETA_DIM + c] = (half_t)(acc[r] + bb);
    }

    {
        int c = tid & 63, rg = tid >> 6;
        float acc[8];
#pragma unroll
        for (int r = 0; r < 8; r++) acc[r] = 0.f;
        for (int k0 = 0; k0 < IN_DIM; k0 += 4) {
            float w0 = Wout[(size_t)(k0 + 0) * OUT_DIM + c];
            float w1 = Wout[(size_t)(k0 + 1) * OUT_DIM + c];
            float w2 = Wout[(size_t)(k0 + 2) * OUT_DIM + c];
            float w3 = Wout[(size_t)(k0 + 3) * OUT_DIM + c];
#pragma unroll
            for (int r = 0; r < 8; r++) {
                float4 h = *(const float4*)&HnS[(rg * 8 + r) * IN_DIM + k0];
                acc[r] += h.x * w0 + h.y * w1 + h.z * w2 + h.w * w3;
            }
        }
        float bb = bout[c];
#pragma unroll
        for (int r = 0; r < 8; r++) Y[(size_t)(row0 + rg * 8 + r) * OUT_DIM + c] = acc[r] + bb;
    }
}

// scores = sigmoid(Hx @ Hx^T); 64x64 tile (4 waves, 32x32 quadrant each) for high occupancy;
// DMA+XOR-swizzle staging; operand-swapped MFMA; inline A-mask epilogue.
__global__ __launch_bounds__(256) void k_scores(const half_t* __restrict__ Hx,
                                                const float* __restrict__ Amat,
                                                float* __restrict__ A1, float* __restrict__ rowsum) {
    __shared__ half_t Rs[64 * 64];
    __shared__ half_t Cs[64 * 64];
    int tid = threadIdx.x;
    int R = blockIdx.x * 64, C = blockIdx.y * 64;
    int lane = tid & 63, wv = tid >> 6;
    int li = lane & 15, lg = lane >> 4;
    int qi = (wv >> 1) * 32, qj = (wv & 1) * 32;   // score-col / score-row quadrant offsets
    int srow = lane >> 3, sunit = lane & 7;

    f32x4 acc[2][2];
#pragma unroll
    for (int t = 0; t < 2; t++)
#pragma unroll
        for (int u = 0; u < 2; u++) acc[t][u] = (f32x4){0.f, 0.f, 0.f, 0.f};

    half_t* HxNC = const_cast<half_t*>(Hx);
    int gunit = (sunit ^ srow) * 8;

    // hoisted epilogue prefetch for u=0
    f32x4 av[2], avn[2];
#pragma unroll
    for (int t = 0; t < 2; t++)
        av[t] = *(const f32x4*)&Amat[(size_t)(R + qj + li) * NN + C + qi + t * 16 + lg * 4];

    for (int s = 0; s < 4; s++) {
        int k0 = s * 64;
        __syncthreads();
#pragma unroll
        for (int c = 0; c < 2; c++) {
            int chunk = wv * 2 + c;              // 8 chunks of 8 rows
            int r = chunk * 8 + srow;
            half_t* gR = HxNC + (size_t)(R + r) * THETA_DIM + k0 + gunit;
            half_t* gC = HxNC + (size_t)(C + r) * THETA_DIM + k0 + gunit;
            __builtin_amdgcn_global_load_lds((AS1 void*)(uintptr_t)gR, (AS3 void*)(Rs + (size_t)chunk * 512), 16, 0, 0);
            __builtin_amdgcn_global_load_lds((AS1 void*)(uintptr_t)gC, (AS3 void*)(Cs + (size_t)chunk * 512), 16, 0, 0);
        }
        __syncthreads();
#pragma unroll
        for (int kk = 0; kk < 2; kk++) {
            int sw = ((kk * 4 + lg) ^ (li & 7)) * 8;
            f16x8 af[2], bf[2];
#pragma unroll
            for (int t = 0; t < 2; t++)
                af[t] = *(const f16x8*)(Cs + (qi + t * 16 + li) * 64 + sw);
#pragma unroll
            for (int u = 0; u < 2; u++)
                bf[u] = *(const f16x8*)(Rs + (qj + u * 16 + li) * 64 + sw);
#pragma unroll
            for (int t = 0; t < 2; t++)
#pragma unroll
                for (int u = 0; u < 2; u++)
                    acc[t][u] = __builtin_amdgcn_mfma_f32_16x16x32_f16(af[t], bf[u], acc[t][u], 0, 0, 0);
        }
    }

    // epilogue: u in {0,1}; per u one score-row per lane; float4 stores; 2-shuffle rowsum.
#pragma unroll
    for (int u = 0; u < 2; u++) {
        int gr = R + qj + u * 16 + li;
        if (u < 1) {
#pragma unroll
            for (int t = 0; t < 2; t++)
                avn[t] = *(const f32x4*)&Amat[(size_t)(gr + 16) * NN + C + qi + t * 16 + lg * 4];
        }
        float rsum = 0.f;
#pragma unroll
        for (int t = 0; t < 2; t++) {
            int gc0 = C + qi + t * 16 + lg * 4;
            float4 wv4;
            float* pv = (float*)&wv4;
#pragma unroll
            for (int jj = 0; jj < 4; jj++) {
                float x = acc[t][u][jj];
                float sg = 1.f / (1.f + __expf(-x));
                float m = (av[t][jj] > 0.f) ? 1.f : 0.f;
                float v = fmaxf(sg, 0.1f) * m + ((gr == gc0 + jj) ? 1.f : 0.f);
                pv[jj] = v;
                rsum += v;
            }
            *(float4*)&A1[(size_t)gr * NN + gc0] = wv4;
        }
        rsum += __shfl_xor(rsum, 16, 64);
        rsum += __shfl_xor(rsum, 32, 64);
        if (lg == 0) atomicAdd(&rowsum[gr], rsum);
        if (u < 1) {
#pragma unroll
            for (int t = 0; t < 2; t++) av[t] = avn[t];
        }
    }
}

// ZdhT[c][j] = (half)(Z[j][c] * rsqrt(rowsum[j]))   [64][8192] f16
__global__ __launch_bounds__(256) void k_scalez(const float* __restrict__ rowsum, const float* __restrict__ Z,
                                                half_t* __restrict__ ZdhT) {
    __shared__ float T[64 * 68];
    int tid = threadIdx.x;
    int j0 = blockIdx.x * 64;
#pragma unroll
    for (int q = 0; q < 4; q++) {
        int unit = q * 256 + tid;
        int j = unit >> 4, c4 = (unit & 15) * 4;
        float dj = rsqrtf(rowsum[j0 + j]);
        float4 v = *(const float4*)&Z[(size_t)(j0 + j) * OUT_DIM + c4];
        v.x *= dj; v.y *= dj; v.z *= dj; v.w *= dj;
        *(float4*)&T[j * 68 + c4] = v;
    }
    __syncthreads();
#pragma unroll
    for (int q = 0; q < 2; q++) {
        int unit = q * 256 + tid;
        int c = unit >> 3, j8 = (unit & 7) * 8;
        f16x8 h;
#pragma unroll
        for (int x = 0; x < 8; x++) h[x] = (half_t)T[(j8 + x) * 68 + c];
        *(f16x8*)&ZdhT[(size_t)c * NN + j0 + j8] = h;
    }
}

// obuf += A1[rows, kslice] @ ZdhT^T  via f16 MFMA; grid (64,32), K-chunk 256 (4 iters), TLP-driven.
__global__ __launch_bounds__(256) void k_spmm(const float* __restrict__ A1, const half_t* __restrict__ ZdhT,
                                              float* __restrict__ obuf) {
    __shared__ half_t As[128 * LSTR];
    __shared__ half_t Bs[64 * LSTR];
    int tid = threadIdx.x;
    int row0 = blockIdx.x * 128;
    int j0 = blockIdx.y * 256;
    int lane = tid & 63, wv = tid >> 6;
    int li = lane & 15, lg = lane >> 4;
    int ar = tid >> 4, ac4 = (tid & 15) * 4;
    int bn = tid >> 3, bk8 = (tid & 7) * 8;

    f32x4 acc[2][4];
#pragma unroll
    for (int t = 0; t < 2; t++)
#pragma unroll
        for (int u = 0; u < 4; u++) acc[t][u] = (f32x4){0.f, 0.f, 0.f, 0.f};

    float4 va[8];
    f16x8 vb[2];
#pragma unroll
    for (int q = 0; q < 8; q++)
        va[q] = *(const float4*)&A1[(size_t)(row0 + (q * 16 + ar)) * NN + j0 + ac4];
#pragma unroll
    for (int q = 0; q < 2; q++)
        vb[q] = *(const f16x8*)&ZdhT[(size_t)(q * 32 + bn) * NN + j0 + bk8];

    for (int jc = j0; jc < j0 + 256; jc += 64) {
        __syncthreads();
#pragma unroll
        for (int q = 0; q < 8; q++) {
            f16x4 h; h[0] = (half_t)va[q].x; h[1] = (half_t)va[q].y; h[2] = (half_t)va[q].z; h[3] = (half_t)va[q].w;
            *(f16x4*)&As[(q * 16 + ar) * LSTR + ac4] = h;
        }
#pragma unroll
        for (int q = 0; q < 2; q++)
            *(f16x8*)&Bs[(q * 32 + bn) * LSTR + bk8] = vb[q];
        if (jc + 64 < j0 + 256) {
#pragma unroll
            for (int q = 0; q < 8; q++)
                va[q] = *(const float4*)&A1[(size_t)(row0 + (q * 16 + ar)) * NN + jc + 64 + ac4];
#pragma unroll
            for (int q = 0; q < 2; q++)
                vb[q] = *(const f16x8*)&ZdhT[(size_t)(q * 32 + bn) * NN + jc + 64 + bk8];
        }
        __syncthreads();
#pragma unroll
        for (int kk = 0; kk < 2; kk++) {
            f16x8 af[2], bf[4];
#pragma unroll
            for (int t = 0; t < 2; t++)
                af[t] = *(const f16x8*)&As[(wv * 32 + t * 16 + li) * LSTR + kk * 32 + lg * 8];
#pragma unroll
            for (int u = 0; u < 4; u++)
                bf[u] = *(const f16x8*)&Bs[(u * 16 + li) * LSTR + kk * 32 + lg * 8];
#pragma unroll
            for (int t = 0; t < 2; t++)
#pragma unroll
                for (int u = 0; u < 4; u++)
                    acc[t][u] = __builtin_amdgcn_mfma_f32_16x16x32_f16(af[t], bf[u], acc[t][u], 0, 0, 0);
        }
    }
#pragma unroll
    for (int t = 0; t < 2; t++)
#pragma unroll
        for (int u = 0; u < 4; u++)
#pragma unroll
            for (int r = 0; r < 4; r++)
                atomicAdd(&obuf[(size_t)(row0 + wv * 32 + t * 16 + lg * 4 + r) * OUT_DIM + u * 16 + li],
                          acc[t][u][r]);
}

__global__ void k_out(const float* __restrict__ ws, float* __restrict__ out) {
    int i = blockIdx.x * 256 + threadIdx.x;
    const float4* O4 = (const float4*)(ws + WS_OBUF);
    int row = i >> 4;
    float d = rsqrtf(ws[WS_ROWSUM + row]);
    float4 v = O4[i];
    float a = d * v.x, b = d * v.y, cc = d * v.z, e = d * v.w;
    v.x = (a >= 0.f) ? a : 0.01f * a;
    v.y = (b >= 0.f) ? b : 0.01f * b;
    v.z = (cc >= 0.f) ? cc : 0.01f * cc;
    v.w = (e >= 0.f) ? e : 0.01f * e;
    ((float4*)out)[i] = v;
}

extern "C" void kernel_launch(void* const* d_in, const int* in_sizes, int n_in,
                              void* d_out, int out_size, void* d_ws, size_t ws_size,
                              hipStream_t stream) {
    const float* H     = (const float*)d_in[0];
    const float* A     = (const float*)d_in[1];
    const float* gamma = (const float*)d_in[2];
    const float* beta  = (const float*)d_in[3];
    const float* W1    = (const float*)d_in[4];
    const float* b1    = (const float*)d_in[5];
    const float* Wout  = (const float*)d_in[6];
    const float* bout  = (const float*)d_in[7];
    float* out = (float*)d_out;
    float* A1  = out + (size_t)NN * OUT_DIM;
    float* ws  = (float*)d_ws;
    half_t* Hx = (half_t*)(ws + WS_HX);
    half_t* ZdhT = (half_t*)(ws + WS_ZDHT);

    k_zero<<<521, 256, 0, stream>>>(ws);
    k_stats<<<256, 256, 0, stream>>>(H, ws);
    k_finalize<<<1, 128, 0, stream>>>(gamma, beta, ws);
    k_proj<<<256, 256, 0, stream>>>(H, ws, W1, b1, Wout, bout, Hx, ws + WS_Z);
    dim3 g6(128, 128);
    k_scores<<<g6, 256, 0, stream>>>(Hx, A, A1, ws + WS_ROWSUM);
    k_scalez<<<128, 256, 0, stream>>>(ws + WS_ROWSUM, ws + WS_Z, ZdhT);
    k_spmm<<<dim3(64, 32), 256, 0, stream>>>(A1, ZdhT, ws + WS_OBUF);
    k_out<<<512, 256, 0, stream>>>(ws, out);
}

// Round 23
// 295.589 us; speedup vs baseline: 1.0600x; 1.0600x over previous
//
#include <hip/hip_runtime.h>
#include <math.h>

#define NN 8192
#define IN_DIM 128
#define THETA_DIM 256
#define OUT_DIM 64
#define LSTR 68   // LDS row stride in halfs (k_spmm only)

#define AS1 __attribute__((address_space(1)))
#define AS3 __attribute__((address_space(3)))

typedef _Float16 half_t;
typedef _Float16 f16x8 __attribute__((ext_vector_type(8)));
typedef _Float16 f16x4 __attribute__((ext_vector_type(4)));
typedef float f32x4 __attribute__((ext_vector_type(4)));

// ws layout (float offsets)
#define WS_SCALE 0
#define WS_SHIFT 128
#define WS_SUM   256
#define WS_SQ    384
#define WS_ROWSUM 512
#define WS_D     8704
#define WS_HN    16896
#define WS_HX    (WS_HN + NN*IN_DIM)
#define WS_Z     (WS_HX + NN*THETA_DIM)
#define WS_OBUF  (WS_Z + NN*OUT_DIM)
#define WS_ZDHT  (WS_OBUF + NN*OUT_DIM)       // f16 [64][8192]

// zero: [WS_SUM, WS_D) = 2112 float4 (9 blocks) + obuf 131072 float4 (512 blocks)
__global__ __launch_bounds__(256) void k_zero(float* __restrict__ ws) {
    int b = blockIdx.x, tid = threadIdx.x;
    float4 z = (float4){0.f, 0.f, 0.f, 0.f};
    if (b < 9) {
        int i = b * 256 + tid;
        if (i < 2112) ((float4*)(ws + WS_SUM))[i] = z;
    } else {
        int i = (b - 9) * 256 + tid;
        ((float4*)(ws + WS_OBUF))[i] = z;
    }
}

__global__ __launch_bounds__(256) void k_stats(const float* __restrict__ H, float* __restrict__ ws) {
    int tid = threadIdx.x;
    int c = tid & 127, h = tid >> 7;
    int rb = blockIdx.x * 32;
    float s = 0.f, q = 0.f;
    for (int r = h; r < 32; r += 2) {
        float v = H[(size_t)(rb + r) * IN_DIM + c];
        s += v; q += v * v;
    }
    atomicAdd(&ws[WS_SUM + c], s);
    atomicAdd(&ws[WS_SQ + c], q);
}

__global__ void k_finalize(const float* __restrict__ gamma, const float* __restrict__ beta, float* __restrict__ ws) {
    int c = threadIdx.x;
    float mean = ws[WS_SUM + c] * (1.f / NN);
    float var  = ws[WS_SQ + c] * (1.f / NN) - mean * mean;
    float rstd = 1.f / sqrtf(var + 1e-5f);
    float sc = rstd * gamma[c];
    ws[WS_SCALE + c] = sc;
    ws[WS_SHIFT + c] = beta[c] - mean * sc;
}

// fused: BN-normalize H tile inline, then Hx = (Hn @ W1 + b1) f16 AND Y = Hn @ Wout + bout
__global__ __launch_bounds__(256) void k_proj(const float* __restrict__ H, const float* __restrict__ ws,
                                              const float* __restrict__ W1, const float* __restrict__ b1,
                                              const float* __restrict__ Wout, const float* __restrict__ bout,
                                              half_t* __restrict__ Hx, float* __restrict__ Y) {
    __shared__ float HnS[32 * IN_DIM];
    int tid = threadIdx.x;
    int row0 = blockIdx.x * 32;
    const float4* src = (const float4*)(H + (size_t)row0 * IN_DIM);
    float4* dst = (float4*)HnS;
#pragma unroll
    for (int q = 0; q < 4; q++) {
        int f4i = q * 256 + tid;
        int cb = (f4i & 31) * 4;
        float4 v = src[f4i];
        float4 sc = *(const float4*)&ws[WS_SCALE + cb];
        float4 sh = *(const float4*)&ws[WS_SHIFT + cb];
        v.x = v.x * sc.x + sh.x; v.y = v.y * sc.y + sh.y;
        v.z = v.z * sc.z + sh.z; v.w = v.w * sc.w + sh.w;
        dst[f4i] = v;
    }
    __syncthreads();

    {
        int c = tid;
        float acc[32];
#pragma unroll
        for (int r = 0; r < 32; r++) acc[r] = 0.f;
        for (int k0 = 0; k0 < IN_DIM; k0 += 4) {
            float w0 = W1[(size_t)(k0 + 0) * THETA_DIM + c];
            float w1 = W1[(size_t)(k0 + 1) * THETA_DIM + c];
            float w2 = W1[(size_t)(k0 + 2) * THETA_DIM + c];
            float w3 = W1[(size_t)(k0 + 3) * THETA_DIM + c];
#pragma unroll
            for (int r = 0; r < 32; r++) {
                float4 h = *(const float4*)&HnS[r * IN_DIM + k0];
                acc[r] += h.x * w0 + h.y * w1 + h.z * w2 + h.w * w3;
            }
        }
        float bb = b1[c];
#pragma unroll
        for (int r = 0; r < 32; r++) Hx[(size_t)(row0 + r) * THETA_DIM + c] = (half_t)(acc[r] + bb);
    }

    {
        int c = tid & 63, rg = tid >> 6;
        float acc[8];
#pragma unroll
        for (int r = 0; r < 8; r++) acc[r] = 0.f;
        for (int k0 = 0; k0 < IN_DIM; k0 += 4) {
            float w0 = Wout[(size_t)(k0 + 0) * OUT_DIM + c];
            float w1 = Wout[(size_t)(k0 + 1) * OUT_DIM + c];
            float w2 = Wout[(size_t)(k0 + 2) * OUT_DIM + c];
            float w3 = Wout[(size_t)(k0 + 3) * OUT_DIM + c];
#pragma unroll
            for (int r = 0; r < 8; r++) {
                float4 h = *(const float4*)&HnS[(rg * 8 + r) * IN_DIM + k0];
                acc[r] += h.x * w0 + h.y * w1 + h.z * w2 + h.w * w3;
            }
        }
        float bb = bout[c];
#pragma unroll
        for (int r = 0; r < 8; r++) Y[(size_t)(row0 + rg * 8 + r) * OUT_DIM + c] = acc[r] + bb;
    }
}

// scores = sigmoid(Hx @ Hx^T); global_load_lds staging with 16B-unit XOR swizzle;
// inline A-mask epilogue with u=0 A-prefetch hoisted above the GEMM.
__global__ __launch_bounds__(256) void k_scores(const half_t* __restrict__ Hx,
                                                const float* __restrict__ Amat,
                                                float* __restrict__ A1, float* __restrict__ rowsum) {
    __shared__ half_t Rs[128 * 64];
    __shared__ half_t Cs[128 * 64];
    int tid = threadIdx.x;
    int R = blockIdx.x * 128, C = blockIdx.y * 128;
    int lane = tid & 63, wv = tid >> 6;
    int li = lane & 15, lg = lane >> 4;
    int qi = (wv >> 1) * 64, qj = (wv & 1) * 64;
    int srow = lane >> 3, sunit = lane & 7;

    f32x4 acc[4][4];
#pragma unroll
    for (int t = 0; t < 4; t++)
#pragma unroll
        for (int u = 0; u < 4; u++) acc[t][u] = (f32x4){0.f, 0.f, 0.f, 0.f};

    half_t* HxNC = const_cast<half_t*>(Hx);
    int gunit = (sunit ^ srow) * 8;

    // hoisted epilogue prefetch for u=0: loads fly under the whole GEMM
    f32x4 av[4], avn[4];
#pragma unroll
    for (int t = 0; t < 4; t++)
        av[t] = *(const f32x4*)&Amat[(size_t)(R + qj + li) * NN + C + qi + t * 16 + lg * 4];

    for (int s = 0; s < 4; s++) {
        int k0 = s * 64;
        __syncthreads();
#pragma unroll
        for (int c = 0; c < 4; c++) {
            int chunk = wv * 4 + c;
            int r = chunk * 8 + srow;
            half_t* gR = HxNC + (size_t)(R + r) * THETA_DIM + k0 + gunit;
            half_t* gC = HxNC + (size_t)(C + r) * THETA_DIM + k0 + gunit;
            __builtin_amdgcn_global_load_lds((AS1 void*)(uintptr_t)gR, (AS3 void*)(Rs + (size_t)chunk * 512), 16, 0, 0);
            __builtin_amdgcn_global_load_lds((AS1 void*)(uintptr_t)gC, (AS3 void*)(Cs + (size_t)chunk * 512), 16, 0, 0);
        }
        __syncthreads();
#pragma unroll
        for (int kk = 0; kk < 2; kk++) {
            int sw = ((kk * 4 + lg) ^ (li & 7)) * 8;
            f16x8 af[4], bf[4];
#pragma unroll
            for (int t = 0; t < 4; t++)
                af[t] = *(const f16x8*)(Cs + (qi + t * 16 + li) * 64 + sw);
#pragma unroll
            for (int u = 0; u < 4; u++)
                bf[u] = *(const f16x8*)(Rs + (qj + u * 16 + li) * 64 + sw);
#pragma unroll
            for (int t = 0; t < 4; t++)
#pragma unroll
                for (int u = 0; u < 4; u++)
                    acc[t][u] = __builtin_amdgcn_mfma_f32_16x16x32_f16(af[t], bf[u], acc[t][u], 0, 0, 0);
        }
    }

    // epilogue: per u one score-row per lane; inline mask from A; float4 stores; 2-shuffle rowsum.
#pragma unroll
    for (int u = 0; u < 4; u++) {
        int gr = R + qj + u * 16 + li;
        if (u < 3) {
#pragma unroll
            for (int t = 0; t < 4; t++)
                avn[t] = *(const f32x4*)&Amat[(size_t)(gr + 16) * NN + C + qi + t * 16 + lg * 4];
        }
        float rsum = 0.f;
#pragma unroll
        for (int t = 0; t < 4; t++) {
            int gc0 = C + qi + t * 16 + lg * 4;
            float4 wv4;
            float* pv = (float*)&wv4;
#pragma unroll
            for (int jj = 0; jj < 4; jj++) {
                float x = acc[t][u][jj];
                float sg = 1.f / (1.f + __expf(-x));
                float m = (av[t][jj] > 0.f) ? 1.f : 0.f;
                float v = fmaxf(sg, 0.1f) * m + ((gr == gc0 + jj) ? 1.f : 0.f);
                pv[jj] = v;
                rsum += v;
            }
            *(float4*)&A1[(size_t)gr * NN + gc0] = wv4;
        }
        rsum += __shfl_xor(rsum, 16, 64);
        rsum += __shfl_xor(rsum, 32, 64);
        if (lg == 0) atomicAdd(&rowsum[gr], rsum);
        if (u < 3) {
#pragma unroll
            for (int t = 0; t < 4; t++) av[t] = avn[t];
        }
    }
}

// ZdhT[c][j] = (half)(Z[j][c] * rsqrt(rowsum[j]))   [64][8192] f16
__global__ __launch_bounds__(256) void k_scalez(const float* __restrict__ rowsum, const float* __restrict__ Z,
                                                half_t* __restrict__ ZdhT) {
    __shared__ float T[64 * 68];
    int tid = threadIdx.x;
    int j0 = blockIdx.x * 64;
#pragma unroll
    for (int q = 0; q < 4; q++) {
        int unit = q * 256 + tid;
        int j = unit >> 4, c4 = (unit & 15) * 4;
        float dj = rsqrtf(rowsum[j0 + j]);
        float4 v = *(const float4*)&Z[(size_t)(j0 + j) * OUT_DIM + c4];
        v.x *= dj; v.y *= dj; v.z *= dj; v.w *= dj;
        *(float4*)&T[j * 68 + c4] = v;
    }
    __syncthreads();
#pragma unroll
    for (int q = 0; q < 2; q++) {
        int unit = q * 256 + tid;
        int c = unit >> 3, j8 = (unit & 7) * 8;
        f16x8 h;
#pragma unroll
        for (int x = 0; x < 8; x++) h[x] = (half_t)T[(j8 + x) * 68 + c];
        *(f16x8*)&ZdhT[(size_t)c * NN + j0 + j8] = h;
    }
}

// obuf += A1[rows, kslice] @ ZdhT^T  via f16 MFMA; grid (64,32), K-chunk 256 (4 iters), TLP-driven.
__global__ __launch_bounds__(256) void k_spmm(const float* __restrict__ A1, const half_t* __restrict__ ZdhT,
                                              float* __restrict__ obuf) {
    __shared__ half_t As[128 * LSTR];
    __shared__ half_t Bs[64 * LSTR];
    int tid = threadIdx.x;
    int row0 = blockIdx.x * 128;
    int j0 = blockIdx.y * 256;
    int lane = tid & 63, wv = tid >> 6;
    int li = lane & 15, lg = lane >> 4;
    int ar = tid >> 4, ac4 = (tid & 15) * 4;
    int bn = tid >> 3, bk8 = (tid & 7) * 8;

    f32x4 acc[2][4];
#pragma unroll
    for (int t = 0; t < 2; t++)
#pragma unroll
        for (int u = 0; u < 4; u++) acc[t][u] = (f32x4){0.f, 0.f, 0.f, 0.f};

    float4 va[8];
    f16x8 vb[2];
#pragma unroll
    for (int q = 0; q < 8; q++)
        va[q] = *(const float4*)&A1[(size_t)(row0 + (q * 16 + ar)) * NN + j0 + ac4];
#pragma unroll
    for (int q = 0; q < 2; q++)
        vb[q] = *(const f16x8*)&ZdhT[(size_t)(q * 32 + bn) * NN + j0 + bk8];

    for (int jc = j0; jc < j0 + 256; jc += 64) {
        __syncthreads();
#pragma unroll
        for (int q = 0; q < 8; q++) {
            f16x4 h; h[0] = (half_t)va[q].x; h[1] = (half_t)va[q].y; h[2] = (half_t)va[q].z; h[3] = (half_t)va[q].w;
            *(f16x4*)&As[(q * 16 + ar) * LSTR + ac4] = h;
        }
#pragma unroll
        for (int q = 0; q < 2; q++)
            *(f16x8*)&Bs[(q * 32 + bn) * LSTR + bk8] = vb[q];
        if (jc + 64 < j0 + 256) {
#pragma unroll
            for (int q = 0; q < 8; q++)
                va[q] = *(const float4*)&A1[(size_t)(row0 + (q * 16 + ar)) * NN + jc + 64 + ac4];
#pragma unroll
            for (int q = 0; q < 2; q++)
                vb[q] = *(const f16x8*)&ZdhT[(size_t)(q * 32 + bn) * NN + jc + 64 + bk8];
        }
        __syncthreads();
#pragma unroll
        for (int kk = 0; kk < 2; kk++) {
            f16x8 af[2], bf[4];
#pragma unroll
            for (int t = 0; t < 2; t++)
                af[t] = *(const f16x8*)&As[(wv * 32 + t * 16 + li) * LSTR + kk * 32 + lg * 8];
#pragma unroll
            for (int u = 0; u < 4; u++)
                bf[u] = *(const f16x8*)&Bs[(u * 16 + li) * LSTR + kk * 32 + lg * 8];
#pragma unroll
            for (int t = 0; t < 2; t++)
#pragma unroll
                for (int u = 0; u < 4; u++)
                    acc[t][u] = __builtin_amdgcn_mfma_f32_16x16x32_f16(af[t], bf[u], acc[t][u], 0, 0, 0);
        }
    }
#pragma unroll
    for (int t = 0; t < 2; t++)
#pragma unroll
        for (int u = 0; u < 4; u++)
#pragma unroll
            for (int r = 0; r < 4; r++)
                atomicAdd(&obuf[(size_t)(row0 + wv * 32 + t * 16 + lg * 4 + r) * OUT_DIM + u * 16 + li],
                          acc[t][u][r]);
}

__global__ void k_out(const float* __restrict__ ws, float* __restrict__ out) {
    int i = blockIdx.x * 256 + threadIdx.x;
    const float4* O4 = (const float4*)(ws + WS_OBUF);
    int row = i >> 4;
    float d = rsqrtf(ws[WS_ROWSUM + row]);
    float4 v = O4[i];
    float a = d * v.x, b = d * v.y, cc = d * v.z, e = d * v.w;
    v.x = (a >= 0.f) ? a : 0.01f * a;
    v.y = (b >= 0.f) ? b : 0.01f * b;
    v.z = (cc >= 0.f) ? cc : 0.01f * cc;
    v.w = (e >= 0.f) ? e : 0.01f * e;
    ((float4*)out)[i] = v;
}

extern "C" void kernel_launch(void* const* d_in, const int* in_sizes, int n_in,
                              void* d_out, int out_size, void* d_ws, size_t ws_size,
                              hipStream_t stream) {
    const float* H     = (const float*)d_in[0];
    const float* A     = (const float*)d_in[1];
    const float* gamma = (const float*)d_in[2];
    const float* beta  = (const float*)d_in[3];
    const float* W1    = (const float*)d_in[4];
    const float* b1    = (const float*)d_in[5];
    const float* Wout  = (const float*)d_in[6];
    const float* bout  = (const float*)d_in[7];
    float* out = (float*)d_out;
    float* A1  = out + (size_t)NN * OUT_DIM;
    float* ws  = (float*)d_ws;
    half_t* Hx = (half_t*)(ws + WS_HX);
    half_t* ZdhT = (half_t*)(ws + WS_ZDHT);

    k_zero<<<521, 256, 0, stream>>>(ws);
    k_stats<<<256, 256, 0, stream>>>(H, ws);
    k_finalize<<<1, 128, 0, stream>>>(gamma, beta, ws);
    k_proj<<<256, 256, 0, stream>>>(H, ws, W1, b1, Wout, bout, Hx, ws + WS_Z);
    dim3 g6(64, 64);
    k_scores<<<g6, 256, 0, stream>>>(Hx, A, A1, ws + WS_ROWSUM);
    k_scalez<<<128, 256, 0, stream>>>(ws + WS_ROWSUM, ws + WS_Z, ZdhT);
    k_spmm<<<dim3(64, 32), 256, 0, stream>>>(A1, ZdhT, ws + WS_OBUF);
    k_out<<<512, 256, 0, stream>>>(ws, out);
}